// Round 14
// baseline (1740.840 us; speedup 1.0000x reference)
//
#include <hip/hip_runtime.h>
#include <hip/hip_bf16.h>

#define DIM 512
#define EPS 1e-8f
#define LN_EPS 1e-5f
#define SCALE 0.04419417382415922f  // 512^-0.5

typedef float f32x4 __attribute__((ext_vector_type(4)));
typedef __bf16 bf16;
typedef __bf16 bf16x8 __attribute__((ext_vector_type(8)));

typedef const __attribute__((address_space(1))) void gvoid;
typedef __attribute__((address_space(3))) void lvoid;

__device__ inline float bf2f_lo(unsigned u) { union { unsigned x; float f; } c; c.x = u << 16; return c.f; }
__device__ inline float bf2f_hi(unsigned u) { union { unsigned x; float f; } c; c.x = u & 0xffff0000u; return c.f; }

// raw barrier with scheduling fences (rule #18: pin mem ops around s_barrier)
#define SBAR() do { __builtin_amdgcn_sched_barrier(0); \
                    __builtin_amdgcn_s_barrier(); \
                    __builtin_amdgcn_sched_barrier(0); } while (0)

// ---------------------------------------------------------------------------
// Row stats (mean, rstd) + fp32 -> bf16 convert, audio+image merged.
__global__ __launch_bounds__(256) void k_stats_convert(
    const float* __restrict__ xa, const float* __restrict__ xi,
    bf16* __restrict__ xbfa, bf16* __restrict__ xbfi,
    float* __restrict__ sa, float* __restrict__ si, int MA)
{
  int row = blockIdx.x * 4 + (threadIdx.x >> 6);
  int lane = threadIdx.x & 63;
  bool isA = row < MA;
  int lrow = isA ? row : row - MA;
  const float* xr = (isA ? xa : xi) + (size_t)lrow * DIM;
  bf16* xbf = (isA ? xbfa : xbfi) + (size_t)lrow * DIM;
  float* stats = (isA ? sa : si) + (size_t)lrow * 2;
  float4 a = *(const float4*)(xr + lane * 8);
  float4 b = *(const float4*)(xr + lane * 8 + 4);
  float s  = a.x + a.y + a.z + a.w + b.x + b.y + b.z + b.w;
  float ss = a.x*a.x + a.y*a.y + a.z*a.z + a.w*a.w
           + b.x*b.x + b.y*b.y + b.z*b.z + b.w*b.w;
  for (int off = 32; off; off >>= 1) { s += __shfl_xor(s, off); ss += __shfl_xor(ss, off); }
  float mean = s * (1.0f / DIM);
  float var  = ss * (1.0f / DIM) - mean * mean;
  float rs   = rsqrtf(var + LN_EPS);
  if (lane == 0) { stats[0] = mean; stats[1] = rs; }
  union { bf16 h[8]; uint4 u; } cv;
  cv.h[0] = (bf16)a.x; cv.h[1] = (bf16)a.y; cv.h[2] = (bf16)a.z; cv.h[3] = (bf16)a.w;
  cv.h[4] = (bf16)b.x; cv.h[5] = (bf16)b.y; cv.h[6] = (bf16)b.z; cv.h[7] = (bf16)b.w;
  *(uint4*)(xbf + lane * 8) = cv.u;
}

// ---------------------------------------------------------------------------
// Row stats only (512 slot rows), one wave per row.
__global__ __launch_bounds__(256) void k_stats512(
    const float* __restrict__ x, float* __restrict__ stats)
{
  int row = blockIdx.x * 4 + (threadIdx.x >> 6);
  int lane = threadIdx.x & 63;
  const float* xr = x + (size_t)row * DIM;
  float4 a = *(const float4*)(xr + lane * 8);
  float4 b = *(const float4*)(xr + lane * 8 + 4);
  float s  = a.x + a.y + a.z + a.w + b.x + b.y + b.z + b.w;
  float ss = a.x*a.x + a.y*a.y + a.z*a.z + a.w*a.w
           + b.x*b.x + b.y*b.y + b.z*b.z + b.w*b.w;
  for (int off = 32; off; off >>= 1) { s += __shfl_xor(s, off); ss += __shfl_xor(ss, off); }
  float mean = s * (1.0f / DIM);
  float rs   = rsqrtf(ss * (1.0f / DIM) - mean * mean + LN_EPS);
  if (lane == 0) { stats[row * 2] = mean; stats[row * 2 + 1] = rs; }
}

// ---------------------------------------------------------------------------
// Weight prep. rows 0..1023: kv bf16 (g_in fold); 1024..1535: Wq' fp32 (g_s);
// 1536..2047: W1' fp32 (g_f). c1 = sum g*W, c2 = sum b*W + bias (split arrays).
__global__ __launch_bounds__(64) void k_prep(
    const float* __restrict__ Wk, const float* __restrict__ bk,
    const float* __restrict__ Wv, const float* __restrict__ bv,
    const float* __restrict__ g_in, const float* __restrict__ b_in,
    const float* __restrict__ Wq, const float* __restrict__ bq,
    const float* __restrict__ g_s, const float* __restrict__ b_s,
    const float* __restrict__ W1, const float* __restrict__ b1,
    const float* __restrict__ g_f, const float* __restrict__ b_f,
    bf16* __restrict__ wbf, float* __restrict__ c1kv, float* __restrict__ c2kv,
    float* __restrict__ Wqp, float* __restrict__ cq1, float* __restrict__ cq2,
    float* __restrict__ W1p, float* __restrict__ cf1, float* __restrict__ cf2)
{
  int n = blockIdx.x; int lane = threadIdx.x;
  if (n < 1024) {
    const float* W = (n < DIM) ? (Wk + (size_t)n * DIM) : (Wv + (size_t)(n - DIM) * DIM);
    float bias = (n < DIM) ? bk[n] : bv[n - DIM];
    float s1 = 0.f, s2 = 0.f;
    union { bf16 h[8]; uint4 u; } cv;
#pragma unroll
    for (int j = 0; j < 8; ++j) {
      int d = lane * 8 + j;
      float w = W[d];
      float gw = g_in[d] * w;
      s1 += gw; s2 += b_in[d] * w;
      cv.h[j] = (bf16)gw;
    }
    *(uint4*)(wbf + (size_t)n * DIM + lane * 8) = cv.u;
    for (int off = 32; off; off >>= 1) { s1 += __shfl_xor(s1, off); s2 += __shfl_xor(s2, off); }
    if (lane == 0) { c1kv[n] = s1; c2kv[n] = s2 + bias; }
  } else {
    int m; const float* W; float bias; const float* g; const float* b;
    float* Wp; float* cc1; float* cc2;
    if (n < 1536) { m = n - 1024; W = Wq + (size_t)m * DIM; bias = bq[m]; g = g_s; b = b_s; Wp = Wqp; cc1 = cq1; cc2 = cq2; }
    else          { m = n - 1536; W = W1 + (size_t)m * DIM; bias = b1[m]; g = g_f; b = b_f; Wp = W1p; cc1 = cf1; cc2 = cf2; }
    float s1 = 0.f, s2 = 0.f;
    float arr[8];
#pragma unroll
    for (int j = 0; j < 8; ++j) {
      int d = lane * 8 + j;
      float w = W[d];
      float gw = g[d] * w;
      s1 += gw; s2 += b[d] * w;
      arr[j] = gw;
    }
    *(float4*)(Wp + (size_t)m * DIM + lane * 8)     = make_float4(arr[0], arr[1], arr[2], arr[3]);
    *(float4*)(Wp + (size_t)m * DIM + lane * 8 + 4) = make_float4(arr[4], arr[5], arr[6], arr[7]);
    for (int off = 32; off; off >>= 1) { s1 += __shfl_xor(s1, off); s2 += __shfl_xor(s2, off); }
    if (lane == 0) { cc1[m] = s1; cc2[m] = s2 + bias; }
  }
}

// ---------------------------------------------------------------------------
// Merged projection GEMM (audio + image, one dispatch). 128x128 tile, BK=32,
// counted-vmcnt 2-buffer pipeline, setprio, XCD chunking, swapped-operand epi.
// 5 blocks/CU (LDS 32KB x 5 = 160KB; VGPR 64 permits it) for +25% TLP.
__global__ __launch_bounds__(256, 5) void k_kv_gemm(
    const bf16* __restrict__ xa, const bf16* __restrict__ xi,
    const bf16* __restrict__ wbf,
    const float* __restrict__ sa, const float* __restrict__ si,
    const float* __restrict__ c1, const float* __restrict__ c2,
    float* __restrict__ ka, float* __restrict__ ki,
    bf16* __restrict__ kba, bf16* __restrict__ kbi,
    bf16* __restrict__ va, bf16* __restrict__ vi,
    int nblkA, int nblkTot)
{
  __shared__ bf16 As[2][128 * 32];
  __shared__ bf16 Bs[2][128 * 32];
  const int t = threadIdx.x, wave = t >> 6, lane = t & 63;
  int bid = blockIdx.x;
  int rid = (bid & 7) * (nblkTot >> 3) + (bid >> 3);   // XCD chunking
  bool isA = rid < nblkA;
  int lrid = isA ? rid : rid - nblkA;
  const bf16* x = isA ? xa : xi;
  const float* stats = isA ? sa : si;
  float* kout = isA ? ka : ki;
  bf16* kbf = isA ? kba : kbi;
  bf16* vbf = isA ? va : vi;
  const int row0 = (lrid >> 3) * 128, col0 = (lrid & 7) * 128;
  f32x4 acc[4][4] = {};   // acc[ni][mi]: reg axis = N, l15 axis = M

  const int sr  = wave * 16 + (lane >> 2);
  const int sgl = ((lane & 3) ^ ((lane >> 3) & 3)) * 8;
  const bf16* asrc = x   + (size_t)(row0 + sr) * DIM + sgl;
  const bf16* bsrc = wbf + (size_t)(col0 + sr) * DIM + sgl;

  auto stage = [&](int buf, int k0) {    // 4 vmem ops per wave
#pragma unroll
    for (int p = 0; p < 2; ++p) {
      __builtin_amdgcn_global_load_lds(
          (gvoid*)(asrc + (size_t)(p * 64) * DIM + k0),
          (lvoid*)((char*)&As[buf][0] + (p * 256 + wave * 64) * 16), 16, 0, 0);
      __builtin_amdgcn_global_load_lds(
          (gvoid*)(bsrc + (size_t)(p * 64) * DIM + k0),
          (lvoid*)((char*)&Bs[buf][0] + (p * 256 + wave * 64) * 16), 16, 0, 0);
    }
  };

  const int l15 = lane & 15, q16 = lane >> 4;
  const int wm = wave >> 1, wn = wave & 1;
  const int gpx = (q16 ^ ((l15 >> 1) & 3)) * 8;   // physical granule elem offset

  stage(0, 0);
  stage(1, 32);
  asm volatile("s_waitcnt vmcnt(4)" ::: "memory");   // buf0's 4 done
  SBAR();
  int cur = 0;
  for (int ks = 0; ks < 16; ++ks) {
    const bf16* Ab = &As[cur][0];
    const bf16* Bb = &Bs[cur][0];
    bf16x8 ax[4], bw[4];
#pragma unroll
    for (int mi = 0; mi < 4; ++mi)
      ax[mi] = *(const bf16x8*)(Ab + (wm * 64 + mi * 16 + l15) * 32 + gpx);
#pragma unroll
    for (int ni = 0; ni < 4; ++ni)
      bw[ni] = *(const bf16x8*)(Bb + (wn * 64 + ni * 16 + l15) * 32 + gpx);
    __builtin_amdgcn_s_setprio(1);
#pragma unroll
    for (int ni = 0; ni < 4; ++ni)
#pragma unroll
      for (int mi = 0; mi < 4; ++mi)
        acc[ni][mi] = __builtin_amdgcn_mfma_f32_16x16x32_bf16(bw[ni], ax[mi], acc[ni][mi], 0, 0, 0);
    __builtin_amdgcn_s_setprio(0);
    if (ks == 15) break;
    SBAR();                                  // all waves done reading buf cur
    if (ks < 14) {
      stage(cur, (ks + 2) * 32);             // restage freed buf; 8 in flight
      asm volatile("s_waitcnt vmcnt(4)" ::: "memory");  // older 4 done
    } else {
      asm volatile("s_waitcnt vmcnt(0)" ::: "memory");  // last tile done
    }
    SBAR();
    cur ^= 1;
  }

  // epilogue: D[n'][m']: n' = q16*4 + reg (first operand = w), m' = l15 (x)
#pragma unroll
  for (int mi = 0; mi < 4; ++mi) {
    int row = row0 + wm * 64 + mi * 16 + l15;
    float2 st = *(const float2*)&stats[row * 2];   // mean, rstd
    float rs = st.y, rm = st.y * st.x;
#pragma unroll
    for (int ni = 0; ni < 4; ++ni) {
      int col = col0 + wn * 64 + ni * 16 + q16 * 4;
      float4 c1v = *(const float4*)&c1[col];
      float4 c2v = *(const float4*)&c2[col];
      f32x4 a = acc[ni][mi];
      float4 o;
      o.x = rs * a[0] - rm * c1v.x + c2v.x;
      o.y = rs * a[1] - rm * c1v.y + c2v.y;
      o.z = rs * a[2] - rm * c1v.z + c2v.z;
      o.w = rs * a[3] - rm * c1v.w + c2v.w;
      union { bf16 h[4]; uint2 u; } pk;
      pk.h[0] = (bf16)o.x; pk.h[1] = (bf16)o.y; pk.h[2] = (bf16)o.z; pk.h[3] = (bf16)o.w;
      if (col0 < DIM) {
        *(float4*)&kout[(size_t)row * DIM + col] = o;
        if (kbf) *(uint2*)&kbf[(size_t)row * DIM + col] = pk.u;
      } else {
        *(uint2*)&vbf[(size_t)row * DIM + (col - DIM)] = pk.u;
      }
    }
  }
}

// ---------------------------------------------------------------------------
// fp32 -> bf16 convert (fallback when kbf couldn't be fused into the GEMM).
__global__ __launch_bounds__(256) void k_f2bf(
    const float* __restrict__ in, bf16* __restrict__ out)
{
  size_t i = ((size_t)blockIdx.x * 256 + threadIdx.x) * 8;
  float4 a = *(const float4*)(in + i);
  float4 b = *(const float4*)(in + i + 4);
  union { bf16 h[8]; uint4 u; } cv;
  cv.h[0] = (bf16)a.x; cv.h[1] = (bf16)a.y; cv.h[2] = (bf16)a.z; cv.h[3] = (bf16)a.w;
  cv.h[4] = (bf16)b.x; cv.h[5] = (bf16)b.y; cv.h[6] = (bf16)b.z; cv.h[7] = (bf16)b.w;
  *(uint4*)(out + i) = cv.u;
}

// ---------------------------------------------------------------------------
// slots init (both modalities share slots0) + fused row stats. 1 block / row.
__global__ __launch_bounds__(256) void k_init_slots(
    const float* __restrict__ noise, const float* __restrict__ mu,
    const float* __restrict__ lsig, float* __restrict__ slots,
    float* __restrict__ stats)
{
  int row = blockIdx.x;            // 256 rows
  int t = threadIdx.x;
  int d1 = t + 256;
  float v0 = mu[t]  + expf(lsig[t])  * noise[row * DIM + t];
  float v1 = mu[d1] + expf(lsig[d1]) * noise[row * DIM + d1];
  slots[(size_t)row * DIM + t]  = v0;
  slots[(size_t)row * DIM + d1] = v1;
  slots[131072 + (size_t)row * DIM + t]  = v0;
  slots[131072 + (size_t)row * DIM + d1] = v1;
  float s = v0 + v1, ss = v0 * v0 + v1 * v1;
  for (int off = 32; off; off >>= 1) { s += __shfl_xor(s, off); ss += __shfl_xor(ss, off); }
  __shared__ float red[8];
  int wv = t >> 6, ln = t & 63;
  if (ln == 0) { red[wv] = s; red[4 + wv] = ss; }
  __syncthreads();
  if (t == 0) {
    s = red[0] + red[1] + red[2] + red[3];
    ss = red[4] + red[5] + red[6] + red[7];
    float mean = s * (1.0f / DIM);
    float rs = rsqrtf(ss * (1.0f / DIM) - mean * mean + LN_EPS);
    stats[row * 2] = mean; stats[row * 2 + 1] = rs;
    stats[(row + 256) * 2] = mean; stats[(row + 256) * 2 + 1] = rs;
  }
}

// ---------------------------------------------------------------------------
// Small fp32 GEMM over 512 joint rows, K=512. MODE:
// 0 Q:    LN-fold -> qbf (scaled); o_q slices only when outA != nullptr
// 3 MLP1: LN-fold + relu -> C
// 4 MLP2: acc + bias + R -> C (+ optional outA/outI slices)
template <int MODE>
__global__ __launch_bounds__(128) void k_sgemm(
    const float* __restrict__ A, const float* __restrict__ B, int N,
    float* __restrict__ C,
    const float* __restrict__ c1a, const float* __restrict__ c2a,
    const float* __restrict__ stats,
    const float* __restrict__ bias, const float* __restrict__ invden,
    const float* __restrict__ R,
    float* __restrict__ outA, float* __restrict__ outI,
    bf16* __restrict__ qbf)
{
  __shared__ float As[32][33];
  __shared__ float Bs[64][33];
  int t = threadIdx.x;
  int m0 = blockIdx.y * 32, n0 = blockIdx.x * 64;
  float acc[4][4] = {};
  for (int k0 = 0; k0 < DIM; k0 += 32) {
    __syncthreads();
#pragma unroll
    for (int p = 0; p < 2; ++p) {
      int idx = p * 128 + t, r = idx >> 3, c4 = (idx & 7) * 4;
      float4 v = *(const float4*)(A + (size_t)(m0 + r) * DIM + k0 + c4);
      As[r][c4] = v.x; As[r][c4 + 1] = v.y; As[r][c4 + 2] = v.z; As[r][c4 + 3] = v.w;
    }
#pragma unroll
    for (int p = 0; p < 4; ++p) {
      int idx = p * 128 + t, r = idx >> 3, c4 = (idx & 7) * 4;
      float4 v = *(const float4*)(B + (size_t)(n0 + r) * DIM + k0 + c4);
      Bs[r][c4] = v.x; Bs[r][c4 + 1] = v.y; Bs[r][c4 + 2] = v.z; Bs[r][c4 + 3] = v.w;
    }
    __syncthreads();
    int tr = t >> 4, tc = t & 15;
#pragma unroll
    for (int k = 0; k < 32; ++k) {
      float a0 = As[tr * 4][k], a1 = As[tr * 4 + 1][k], a2 = As[tr * 4 + 2][k], a3 = As[tr * 4 + 3][k];
      float b0 = Bs[tc * 4][k], b1 = Bs[tc * 4 + 1][k], b2 = Bs[tc * 4 + 2][k], b3 = Bs[tc * 4 + 3][k];
      acc[0][0] += a0 * b0; acc[0][1] += a0 * b1; acc[0][2] += a0 * b2; acc[0][3] += a0 * b3;
      acc[1][0] += a1 * b0; acc[1][1] += a1 * b1; acc[1][2] += a1 * b2; acc[1][3] += a1 * b3;
      acc[2][0] += a2 * b0; acc[2][1] += a2 * b1; acc[2][2] += a2 * b2; acc[2][3] += a2 * b3;
      acc[3][0] += a3 * b0; acc[3][1] += a3 * b1; acc[3][2] += a3 * b2; acc[3][3] += a3 * b3;
    }
  }
  int tr = t >> 4, tc = t & 15;
#pragma unroll
  for (int mi = 0; mi < 4; ++mi) {
    int row = m0 + tr * 4 + mi;
#pragma unroll
    for (int ni = 0; ni < 4; ++ni) {
      int col = n0 + tc * 4 + ni;
      float v = acc[mi][ni];
      if (MODE == 0 || MODE == 3) {
        float mean = stats[row * 2], rs = stats[row * 2 + 1];
        v = rs * v - rs * mean * c1a[col] + c2a[col];
      }
      if (MODE == 4) v += bias[col];
      if (MODE == 3) v = fmaxf(v, 0.0f);
      if (MODE == 4) v += R[(size_t)row * N + col];
      if (MODE == 0) {
        if (outA) {
          if (row < 256) outA[(size_t)row * DIM + col] = v;
          else           outI[(size_t)(row - 256) * DIM + col] = v;
        }
        qbf[(size_t)row * DIM + col] = (bf16)(v * SCALE);
      } else {
        C[(size_t)row * N + col] = v;
        if (MODE == 4 && outA) {
          if (row < 256) outA[(size_t)row * DIM + col] = v;
          else           outI[(size_t)(row - 256) * DIM + col] = v;
        }
      }
    }
  }
}

// ---------------------------------------------------------------------------
// Fused GRU gate GEMMs: blocks x<24 compute gib = (num @ W_ih^T)*invden + b_ih,
// blocks x>=24 compute ghb = slots @ W_hh^T + b_hh. N = 1536. grid (48, 16).
__global__ __launch_bounds__(128) void k_gates(
    const float* __restrict__ num, const float* __restrict__ slots,
    const float* __restrict__ Wih, const float* __restrict__ Whh,
    const float* __restrict__ bih, const float* __restrict__ bhh,
    const float* __restrict__ invden,
    float* __restrict__ gib, float* __restrict__ ghb)
{
  bool first = blockIdx.x < 24;
  const float* A = first ? num : slots;
  const float* B = first ? Wih : Whh;
  const float* bias = first ? bih : bhh;
  float* C = first ? gib : ghb;
  int n0 = (first ? blockIdx.x : blockIdx.x - 24) * 64;
  int m0 = blockIdx.y * 32;
  __shared__ float As[32][33];
  __shared__ float Bs[64][33];
  int t = threadIdx.x;
  float acc[4][4] = {};
  for (int k0 = 0; k0 < DIM; k0 += 32) {
    __syncthreads();
#pragma unroll
    for (int p = 0; p < 2; ++p) {
      int idx = p * 128 + t, r = idx >> 3, c4 = (idx & 7) * 4;
      float4 v = *(const float4*)(A + (size_t)(m0 + r) * DIM + k0 + c4);
      As[r][c4] = v.x; As[r][c4 + 1] = v.y; As[r][c4 + 2] = v.z; As[r][c4 + 3] = v.w;
    }
#pragma unroll
    for (int p = 0; p < 4; ++p) {
      int idx = p * 128 + t, r = idx >> 3, c4 = (idx & 7) * 4;
      float4 v = *(const float4*)(B + (size_t)(n0 + r) * DIM + k0 + c4);
      Bs[r][c4] = v.x; Bs[r][c4 + 1] = v.y; Bs[r][c4 + 2] = v.z; Bs[r][c4 + 3] = v.w;
    }
    __syncthreads();
    int tr = t >> 4, tc = t & 15;
#pragma unroll
    for (int k = 0; k < 32; ++k) {
      float a0 = As[tr * 4][k], a1 = As[tr * 4 + 1][k], a2 = As[tr * 4 + 2][k], a3 = As[tr * 4 + 3][k];
      float b0 = Bs[tc * 4][k], b1 = Bs[tc * 4 + 1][k], b2 = Bs[tc * 4 + 2][k], b3 = Bs[tc * 4 + 3][k];
      acc[0][0] += a0 * b0; acc[0][1] += a0 * b1; acc[0][2] += a0 * b2; acc[0][3] += a0 * b3;
      acc[1][0] += a1 * b0; acc[1][1] += a1 * b1; acc[1][2] += a1 * b2; acc[1][3] += a1 * b3;
      acc[2][0] += a2 * b0; acc[2][1] += a2 * b1; acc[2][2] += a2 * b2; acc[2][3] += a2 * b3;
      acc[3][0] += a3 * b0; acc[3][1] += a3 * b1; acc[3][2] += a3 * b2; acc[3][3] += a3 * b3;
    }
  }
  int tr = t >> 4, tc = t & 15;
#pragma unroll
  for (int mi = 0; mi < 4; ++mi) {
    int row = m0 + tr * 4 + mi;
    float sc = first ? invden[row] : 1.0f;
#pragma unroll
    for (int ni = 0; ni < 4; ++ni) {
      int col = n0 + tc * 4 + ni;
      C[(size_t)row * 1536 + col] = acc[mi][ni] * sc + bias[col];
    }
  }
}

// ---------------------------------------------------------------------------
// FUSED dots + slot-softmax + a@v partials. Phase 2: 16B/lane v loads
// (dim-group x row-group decomposition) + LDS reduce across row-groups.
template <int LAST>
__global__ __launch_bounds__(256) void k_dots_upd(
    const bf16* __restrict__ qA, const bf16* __restrict__ qI,
    const bf16* __restrict__ kA, const bf16* __restrict__ kI,
    const bf16* __restrict__ vA, const bf16* __restrict__ vI,
    float* __restrict__ aoutA, float* __restrict__ aoutI,
    float* __restrict__ acA, float* __restrict__ acI,
    float* __restrict__ denp, float* __restrict__ denpc,
    float* __restrict__ numpA, float* __restrict__ numpI,
    int NA_, int NI_)
{
  __shared__ bf16 ks[2][128 * 64];   // 32 KB, swizzled k tiles / phase-2 scratch
  __shared__ float ash[128 * 12];    // 6 KB a-tile
  __shared__ float dsh[64];
  int t = threadIdx.x, wave = t >> 6, lane = t & 63;
  int b = blockIdx.y, tile = blockIdx.x;
  bool isA = tile < 8;
  int til = isA ? tile : tile - 8;
  int N = isA ? NA_ : NI_;
  int nc = isA ? 8 : 25;
  int j0 = til * 128;
  const bf16* qo = (isA ? qA : qI) + (size_t)b * 8 * DIM;
  const bf16* qc = (isA ? qI : qA) + (size_t)b * 8 * DIM;
  const bf16* k  = (isA ? kA : kI) + (size_t)b * N * DIM;
  const bf16* v  = (isA ? vA : vI) + (size_t)b * N * DIM;
  float* aout = (isA ? aoutA : aoutI) + (LAST ? (size_t)b * 8 * N : 0);
  float* aco  = (isA ? acA  : acI ) + (LAST ? (size_t)b * 8 * N : 0);
  int drow = (isA ? 0 : 256) + b * 8;

  const int l15 = lane & 15, q16 = lane >> 4;
  bf16x8 afq[16], afqc[16];
  {
    const bf16* qr = qo + (size_t)(l15 & 7) * DIM + q16 * 8;
#pragma unroll
    for (int f = 0; f < 16; ++f) afq[f] = *(const bf16x8*)(qr + f * 32);
  }
  if (LAST) {
    const bf16* qr = qc + (size_t)(l15 & 7) * DIM + q16 * 8;
#pragma unroll
    for (int f = 0; f < 16; ++f) afqc[f] = *(const bf16x8*)(qr + f * 32);
  }

  const int sr  = wave * 8 + (lane >> 3);
  const int sgl = ((lane & 7) ^ (lane >> 3)) * 8;
  int jr = j0 + sr; if (jr > N - 1) jr = N - 1;
  const bf16* ksrc = k + (size_t)jr * DIM + sgl;
  int jr2 = j0 + 32 + sr; if (jr2 > N - 1) jr2 = N - 1;
  const bf16* ksrc2 = k + (size_t)jr2 * DIM + sgl;
  int jr3 = j0 + 64 + sr; if (jr3 > N - 1) jr3 = N - 1;
  const bf16* ksrc3 = k + (size_t)jr3 * DIM + sgl;
  int jr4 = j0 + 96 + sr; if (jr4 > N - 1) jr4 = N - 1;
  const bf16* ksrc4 = k + (size_t)jr4 * DIM + sgl;

  auto stage = [&](int buf, int c) {   // 4 vmem ops per wave
    __builtin_amdgcn_global_load_lds((gvoid*)(ksrc  + c * 64),
        (lvoid*)((char*)&ks[0][0] + buf * 16384 + (0 * 256 + wave * 64) * 16), 16, 0, 0);
    __builtin_amdgcn_global_load_lds((gvoid*)(ksrc2 + c * 64),
        (lvoid*)((char*)&ks[0][0] + buf * 16384 + (1 * 256 + wave * 64) * 16), 16, 0, 0);
    __builtin_amdgcn_global_load_lds((gvoid*)(ksrc3 + c * 64),
        (lvoid*)((char*)&ks[0][0] + buf * 16384 + (2 * 256 + wave * 64) * 16), 16, 0, 0);
    __builtin_amdgcn_global_load_lds((gvoid*)(ksrc4 + c * 64),
        (lvoid*)((char*)&ks[0][0] + buf * 16384 + (3 * 256 + wave * 64) * 16), 16, 0, 0);
  };

  stage(0, 0);
  stage(1, 1);
  asm volatile("s_waitcnt vmcnt(4)" ::: "memory");
  SBAR();
  f32x4 acc[2] = {}, accc[2] = {};
  int cur = 0;
  for (int c = 0; c < 8; ++c) {
    const bf16* kb = &ks[0][0] + cur * (128 * 64);
    __builtin_amdgcn_s_setprio(1);
#pragma unroll
    for (int kk = 0; kk < 2; ++kk) {
#pragma unroll
      for (int n = 0; n < 2; ++n) {
        int R = wave * 32 + n * 16 + l15;
        int gp = (kk * 4 + q16) ^ (R & 7);
        bf16x8 bfr = *(const bf16x8*)(kb + R * 64 + gp * 8);
        acc[n] = __builtin_amdgcn_mfma_f32_16x16x32_bf16(afq[c * 2 + kk], bfr, acc[n], 0, 0, 0);
        if (LAST)
          accc[n] = __builtin_amdgcn_mfma_f32_16x16x32_bf16(afqc[c * 2 + kk], bfr, accc[n], 0, 0, 0);
      }
    }
    __builtin_amdgcn_s_setprio(0);
    if (c == 7) break;
    SBAR();
    if (c < 6) {
      stage(cur, c + 2);
      asm volatile("s_waitcnt vmcnt(4)" ::: "memory");
    } else {
      asm volatile("s_waitcnt vmcnt(0)" ::: "memory");
    }
    SBAR();
    cur ^= 1;
  }

  // epilogue: q16 groups hold slots 0-3 / 4-7 for token col = lane&15
  float dsum[8], dsumc[8];
#pragma unroll
  for (int i = 0; i < 8; ++i) { dsum[i] = 0.f; dsumc[i] = 0.f; }
#pragma unroll
  for (int n = 0; n < 2; ++n) {
    int jloc = wave * 32 + n * 16 + l15;
    int j = j0 + jloc;
    bool valid = (j < N);
    {
      float dv[8];
#pragma unroll
      for (int r = 0; r < 4; ++r) {
        float own = acc[n][r];
        float oth = __shfl_xor(own, 16);
        if (q16 == 0) { dv[r] = own; dv[4 + r] = oth; }
        else          { dv[r] = oth; dv[4 + r] = own; }
      }
      float mx = dv[0];
#pragma unroll
      for (int i = 1; i < 8; ++i) mx = fmaxf(mx, dv[i]);
      float sum = 0.f;
#pragma unroll
      for (int i = 0; i < 8; ++i) { dv[i] = __expf(dv[i] - mx); sum += dv[i]; }
      float inv = 1.0f / sum;
#pragma unroll
      for (int i = 0; i < 8; ++i) {
        float av = valid ? dv[i] * inv : 0.0f;
        dsum[i] += av;
        if (q16 == 0) {
          ash[jloc * 12 + i] = av;
          if (LAST && valid) aout[(size_t)i * N + j] = av;
        }
      }
    }
    if (LAST) {
      float dv[8];
#pragma unroll
      for (int r = 0; r < 4; ++r) {
        float own = accc[n][r];
        float oth = __shfl_xor(own, 16);
        if (q16 == 0) { dv[r] = own; dv[4 + r] = oth; }
        else          { dv[r] = oth; dv[4 + r] = own; }
      }
      float mx = dv[0];
#pragma unroll
      for (int i = 1; i < 8; ++i) mx = fmaxf(mx, dv[i]);
      float sum = 0.f;
#pragma unroll
      for (int i = 0; i < 8; ++i) { dv[i] = __expf(dv[i] - mx); sum += dv[i]; }
      float inv = 1.0f / sum;
#pragma unroll
      for (int i = 0; i < 8; ++i) {
        float av = valid ? dv[i] * inv : 0.0f;
        dsumc[i] += av;
        if (q16 == 0 && valid) aco[(size_t)i * N + j] = av;
      }
    }
  }
#pragma unroll
  for (int i = 0; i < 8; ++i) {
    float x1 = dsum[i];
    x1 += __shfl_xor(x1, 1); x1 += __shfl_xor(x1, 2);
    x1 += __shfl_xor(x1, 4); x1 += __shfl_xor(x1, 8);
    dsum[i] = x1;
    if (LAST) {
      float x2 = dsumc[i];
      x2 += __shfl_xor(x2, 1); x2 += __shfl_xor(x2, 2);
      x2 += __shfl_xor(x2, 4); x2 += __shfl_xor(x2, 8);
      dsumc[i] = x2;
    }
  }
  if (lane == 0) {
#pragma unroll
    for (int i = 0; i < 8; ++i) {
      dsh[wave * 8 + i] = dsum[i];
      if (LAST) dsh[32 + wave * 8 + i] = dsumc[i];
    }
  }
  __syncthreads();   // also: all ks reads (MFMA phase) complete past here
  if (t < 8) {
    denp[((size_t)drow + t) * 32 + til] = dsh[t] + dsh[8 + t] + dsh[16 + t] + dsh[24 + t];
  }
  if (LAST && t >= 8 && t < 16) {
    int i = t - 8;
    denpc[((size_t)drow + i) * 32 + til] = dsh[32 + i] + dsh[40 + i] + dsh[48 + i] + dsh[56 + i];
  }

  // ---- phase 2: num partial = a(tile) @ v(tile), 16B/lane v loads ----
  int dg = t & 63, rg = t >> 6;
  float ua[8][8];
#pragma unroll
  for (int i = 0; i < 8; ++i)
#pragma unroll
    for (int j = 0; j < 8; ++j) ua[i][j] = 0.f;
  for (int jj = rg; jj < 128; jj += 4) {
    int jv = j0 + jj; if (jv > N - 1) jv = N - 1;   // a==0 for padded rows
    uint4 vv = *(const uint4*)(v + (size_t)jv * DIM + dg * 8);
    float vf[8];
    vf[0] = bf2f_lo(vv.x); vf[1] = bf2f_hi(vv.x);
    vf[2] = bf2f_lo(vv.y); vf[3] = bf2f_hi(vv.y);
    vf[4] = bf2f_lo(vv.z); vf[5] = bf2f_hi(vv.z);
    vf[6] = bf2f_lo(vv.w); vf[7] = bf2f_hi(vv.w);
    float4 a0 = *(const float4*)&ash[jj * 12];
    float4 a1 = *(const float4*)&ash[jj * 12 + 4];
    float aw[8] = {a0.x, a0.y, a0.z, a0.w, a1.x, a1.y, a1.z, a1.w};
#pragma unroll
    for (int i = 0; i < 8; ++i)
#pragma unroll
      for (int j = 0; j < 8; ++j)
        ua[i][j] += aw[i] * vf[j];
  }
  float* red2 = (float*)&ks[0][0];   // 32 KB scratch: [16][512] f32
  float* np = (isA ? numpA : numpI) + (((size_t)b * nc + til) * 8) * DIM;
#pragma unroll
  for (int sg = 0; sg < 2; ++sg) {
    __syncthreads();
#pragma unroll
    for (int i4 = 0; i4 < 4; ++i4) {
      int i = sg * 4 + i4;
      *(float4*)&red2[(i4 * 4 + rg) * 512 + dg * 8]     = make_float4(ua[i][0], ua[i][1], ua[i][2], ua[i][3]);
      *(float4*)&red2[(i4 * 4 + rg) * 512 + dg * 8 + 4] = make_float4(ua[i][4], ua[i][5], ua[i][6], ua[i][7]);
    }
    __syncthreads();
    {
      int i4r = t >> 6;          // slot within group
      int d0r = (t & 63) * 8;    // 8 consecutive dims
      float o[8];
#pragma unroll
      for (int j = 0; j < 8; ++j) {
        int d = d0r + j;
        o[j] = red2[(i4r * 4 + 0) * 512 + d] + red2[(i4r * 4 + 1) * 512 + d]
             + red2[(i4r * 4 + 2) * 512 + d] + red2[(i4r * 4 + 3) * 512 + d];
      }
      *(float4*)&np[(size_t)(sg * 4 + i4r) * DIM + d0r]     = make_float4(o[0], o[1], o[2], o[3]);
      *(float4*)&np[(size_t)(sg * 4 + i4r) * DIM + d0r + 4] = make_float4(o[4], o[5], o[6], o[7]);
    }
  }
}

// ---------------------------------------------------------------------------
// num reduce over tile partials + invden = 1/(sum denp + EPS). 1 block / row.
__global__ __launch_bounds__(256) void k_numred(
    const float* __restrict__ numpA, const float* __restrict__ numpI,
    const float* __restrict__ denp,
    float* __restrict__ num, float* __restrict__ invden)
{
  int m = blockIdx.x, t = threadIdx.x;
  bool isA = m < 256;
  int mm = isA ? m : m - 256;
  int bb = mm >> 3, i = mm & 7;
  int nc = isA ? 8 : 25;
  const float* np = (isA ? numpA : numpI) + (((size_t)bb * nc) * 8 + i) * DIM;
  int d0 = t * 2;
  float s0 = 0.f, s1 = 0.f;
  for (int c = 0; c < nc; ++c) {
    float2 vv = *(const float2*)&np[(size_t)c * 8 * DIM + d0];
    s0 += vv.x; s1 += vv.y;
  }
  *(float2*)&num[(size_t)m * DIM + d0] = make_float2(s0, s1);
  if (t == 0) {
    float den = EPS;
    for (int c2 = 0; c2 < nc; ++c2) den += denp[(size_t)m * 32 + c2];
    invden[m] = 1.0f / den;
  }
}

// ---------------------------------------------------------------------------
// GRU pointwise (gate order r,z,n) + stats of h. One block per row.
__global__ __launch_bounds__(256) void k_gru(
    const float* __restrict__ gi, const float* __restrict__ gh,
    const float* __restrict__ prev,
    float* __restrict__ hout, float* __restrict__ stats_h)
{
  int m = blockIdx.x; int t = threadIdx.x;
  size_t b3 = (size_t)m * 1536, b1 = (size_t)m * DIM;
  float h[2]; float s = 0.f, ss = 0.f;
#pragma unroll
  for (int p = 0; p < 2; ++p) {
    int d = t + p * 256;
    float ir = gi[b3 + d], iz = gi[b3 + 512 + d], in_ = gi[b3 + 1024 + d];
    float hr = gh[b3 + d], hz = gh[b3 + 512 + d], hn = gh[b3 + 1024 + d];
    float r = 1.f / (1.f + __expf(-(ir + hr)));
    float z = 1.f / (1.f + __expf(-(iz + hz)));
    float n = tanhf(in_ + r * hn);
    float hv = (1.f - z) * n + z * prev[b1 + d];
    hout[b1 + d] = hv;
    h[p] = hv; s += hv; ss += hv * hv;
  }
  for (int off = 32; off; off >>= 1) { s += __shfl_xor(s, off); ss += __shfl_xor(ss, off); }
  __shared__ float red[8];
  int wv = t >> 6, ln = t & 63;
  if (ln == 0) { red[wv] = s; red[4 + wv] = ss; }
  __syncthreads();
  s = red[0] + red[1] + red[2] + red[3];
  ss = red[4] + red[5] + red[6] + red[7];
  float mean = s * (1.0f / DIM);
  float rs = rsqrtf(ss * (1.0f / DIM) - mean * mean + LN_EPS);
  if (t == 0) { stats_h[m * 2] = mean; stats_h[m * 2 + 1] = rs; }
}

// ---------------------------------------------------------------------------
// attn/cross = a / (sum_j a + EPS). grid (512, 2): y=0 own attn, y=1 cross.
__global__ __launch_bounds__(256) void k_renorm2(
    const float* __restrict__ aA, const float* __restrict__ aI,
    const float* __restrict__ acA, const float* __restrict__ acI,
    const float* __restrict__ denp, const float* __restrict__ denpc,
    float* __restrict__ oaA, float* __restrict__ oaI,
    float* __restrict__ ocIA, float* __restrict__ ocAI, int NA_, int NI_)
{
  int m = blockIdx.x; int t = threadIdx.x;
  bool cr = blockIdx.y != 0;
  bool isA = m < 256;
  int mm = isA ? m : m - 256;
  int N = isA ? NA_ : NI_;
  int nch = isA ? 8 : 25;
  const float* in = (cr ? (isA ? acA : acI) : (isA ? aA : aI)) + (size_t)mm * N;
  const float* dp = cr ? denpc : denp;
  float* out = (cr ? (isA ? ocIA : ocAI) : (isA ? oaA : oaI)) + (size_t)mm * N;
  float den = EPS;
  for (int c = 0; c < nch; ++c) den += dp[(size_t)m * 32 + c];
  float inv = 1.0f / den;
  for (int idx = t; idx * 4 < N; idx += 256) {
    float4 v = *(const float4*)&in[idx * 4];
    v.x *= inv; v.y *= inv; v.z *= inv; v.w *= inv;
    *(float4*)&out[idx * 4] = v;
  }
}

// ---------------------------------------------------------------------------
extern "C" void kernel_launch(void* const* d_in, const int* in_sizes, int n_in,
                              void* d_out, int out_size, void* d_ws, size_t ws_size,
                              hipStream_t stream)
{
  (void)in_sizes; (void)n_in; (void)out_size;
  const float* x_a   = (const float*)d_in[0];
  const float* x_i   = (const float*)d_in[1];
  const float* noise = (const float*)d_in[2];
  const float* mu    = (const float*)d_in[3];
  const float* lsig  = (const float*)d_in[4];
  const float* ln_in_g = (const float*)d_in[5];
  const float* ln_in_b = (const float*)d_in[6];
  const float* ln_s_g  = (const float*)d_in[7];
  const float* ln_s_b  = (const float*)d_in[8];
  const float* ln_f_g  = (const float*)d_in[9];
  const float* ln_f_b  = (const float*)d_in[10];
  const float* Wq = (const float*)d_in[11]; const float* bq = (const float*)d_in[12];
  const float* Wk = (const float*)d_in[13]; const float* bk = (const float*)d_in[14];
  const float* Wv = (const float*)d_in[15]; const float* bv = (const float*)d_in[16];
  const float* W_ih = (const float*)d_in[17]; const float* W_hh = (const float*)d_in[18];
  const float* b_ih = (const float*)d_in[19]; const float* b_hh = (const float*)d_in[20];
  const float* W1 = (const float*)d_in[21]; const float* b1 = (const float*)d_in[22];
  const float* W2 = (const float*)d_in[23]; const float* b2 = (const float*)d_in[24];

  const int NA = 1024, NI = 3136;
  const int MA = 32 * NA, MI = 32 * NI;     // 32768, 100352

  float* out = (float*)d_out;
  float* o_slots_a  = out;
  float* o_q_a      = out + 131072;
  float* o_k_a      = out + 262144;
  float* o_attn_a   = out + 17039360;
  float* o_cross_ia = out + 17301504;
  float* o_slots_i  = out + 17563648;
  float* o_q_i      = out + 17694720;
  float* o_k_i      = out + 17825792;
  float* o_attn_i   = out + 69206016;
  float* o_cross_ai = out + 70008832;

  // ---- workspace carve ----
  char* w = (char*)d_ws;
  size_t used = 0;
  auto alloc = [&](size_t bytes) {
    char* p = w + used;
    used += (bytes + 255) & ~(size_t)255;
    return p;
  };
  bf16* xbf_a = (bf16*)alloc((size_t)MA * DIM * 2);
  bf16* xbf_i = (bf16*)alloc((size_t)MI * DIM * 2);
  bf16* vbf_a = (bf16*)alloc((size_t)MA * DIM * 2);
  bf16* vbf_i = (bf16*)alloc((size_t)MI * DIM * 2);
  float* stats_a = (float*)alloc((size_t)MA * 2 * 4);
  float* stats_i = (float*)alloc((size_t)MI * 2 * 4);
  bf16* wbf  = (bf16*)alloc(1024 * 512 * 2);
  float* c1kv = (float*)alloc(1024 * 4);
  float* c2kv = (float*)alloc(1024 * 4);
  float* Wqp = (float*)alloc(512 * 512 * 4);
  float* cq1 = (float*)alloc(512 * 4);
  float* cq2 = (float*)alloc(512 * 4);
  float* W1p = (float*)alloc(512 * 512 * 4);
  float* cf1 = (float*)alloc(512 * 4);
  float* cf2 = (float*)alloc(512 * 4);
  float* slots = (float*)alloc(512 * 512 * 4);
  bf16*  qbf   = (bf16*)alloc(512 * 512 * 2);
  float* mid   = (float*)alloc(512 * 512 * 4);
  float* hid   = (float*)alloc(512 * 512 * 4);
  float* num   = (float*)alloc(512 * 512 * 4);
  float* gib   = (float*)alloc(512 * 1536 * 4);
  float* ghb   = (float*)alloc(512 * 1536 * 4);
  float* stats_s = (float*)alloc(512 * 2 * 4);
  float* stats_h = (float*)alloc(512 * 2 * 4);
  float* invden  = (float*)alloc(512 * 4);
  float* denp    = (float*)alloc(512 * 32 * 4);
  float* denpc   = (float*)alloc(512 * 32 * 4);
  float* abuf_a  = (float*)alloc((size_t)256 * NA * 4);
  float* abuf_i  = (float*)alloc((size_t)256 * NI * 4);
  float* abufc_a = (float*)alloc((size_t)256 * NA * 4);
  float* abufc_i = (float*)alloc((size_t)256 * NI * 4);
  float* numpA   = (float*)alloc((size_t)32 * 8 * 8 * DIM * 4);
  float* numpI   = (float*)alloc((size_t)32 * 25 * 8 * DIM * 4);
  if (used > ws_size) return;   // base ws too small -> diagnosable poison

  size_t kbf_bytes = (((size_t)MA * DIM * 2 + 255) & ~(size_t)255)
                   + (((size_t)MI * DIM * 2 + 255) & ~(size_t)255);
  bf16* kbf_a; bf16* kbf_i; bool kbf_fused;
  if (used + kbf_bytes <= ws_size) {
    kbf_a = (bf16*)alloc((size_t)MA * DIM * 2);
    kbf_i = (bf16*)alloc((size_t)MI * DIM * 2);
    kbf_fused = true;
  } else {
    kbf_a = xbf_a; kbf_i = xbf_i;   // reuse, filled by k_f2bf after the GEMMs
    kbf_fused = false;
  }

  // ---- phase 1 ----
  k_stats_convert<<<(MA + MI) / 4, 256, 0, stream>>>(x_a, x_i, xbf_a, xbf_i,
                                                     stats_a, stats_i, MA);
  k_prep<<<2048, 64, 0, stream>>>(Wk, bk, Wv, bv, ln_in_g, ln_in_b,
                                  Wq, bq, ln_s_g, ln_s_b, W1, b1, ln_f_g, ln_f_b,
                                  wbf, c1kv, c2kv, Wqp, cq1, cq2, W1p, cf1, cf2);
  {
    int nblkA = (MA / 128) * 8;           // 2048
    int nblkTot = nblkA + (MI / 128) * 8; // 8320 (divisible by 8)
    k_kv_gemm<<<nblkTot, 256, 0, stream>>>(xbf_a, xbf_i, wbf, stats_a, stats_i,
        c1kv, c2kv, o_k_a, o_k_i,
        kbf_fused ? kbf_a : nullptr, kbf_fused ? kbf_i : nullptr,
        vbf_a, vbf_i, nblkA, nblkTot);
  }
  if (!kbf_fused) {
    k_f2bf<<<MA * DIM / 2048, 256, 0, stream>>>(o_k_a, kbf_a);
    k_f2bf<<<MI * DIM / 2048, 256, 0, stream>>>(o_k_i, kbf_i);
  }
  k_init_slots<<<256, 256, 0, stream>>>(noise, mu, lsig, slots, stats_s);

  // ---- iterations ----
  for (int it = 0; it < 3; ++it) {
    bool last = (it == 2);
    // q = LN(slots) @ Wq' + fold  -> qbf (scaled); o_q only on last iter
    k_sgemm<0><<<dim3(8, 16), 128, 0, stream>>>(slots, Wqp, DIM, nullptr,
        cq1, cq2, stats_s, nullptr, nullptr, nullptr,
        last ? o_q_a : nullptr, last ? o_q_i : nullptr, qbf);
    // fused dots + softmax + a@v partials (+ cross dots on last iter)
    if (!last)
      k_dots_upd<0><<<dim3(33, 32), 256, 0, stream>>>(qbf, qbf + 256 * DIM,
          kbf_a, kbf_i, vbf_a, vbf_i,
          nullptr, nullptr, nullptr, nullptr, denp, nullptr,
          numpA, numpI, NA, NI);
    else
      k_dots_upd<1><<<dim3(33, 32), 256, 0, stream>>>(qbf, qbf + 256 * DIM,
          kbf_a, kbf_i, vbf_a, vbf_i,
          abuf_a, abuf_i, abufc_a, abufc_i, denp, denpc,
          numpA, numpI, NA, NI);
    k_numred<<<512, 256, 0, stream>>>(numpA, numpI, denp, num, invden);
    // fused GRU gate GEMMs
    k_gates<<<dim3(48, 16), 128, 0, stream>>>(num, slots, W_ih, W_hh,
        b_ih, b_hh, invden, gib, ghb);
    k_gru<<<512, 256, 0, stream>>>(gib, ghb, slots, mid, stats_h);
    // MLP (ln_ff folded into W1')
    k_sgemm<3><<<dim3(8, 16), 128, 0, stream>>>(mid, W1p, DIM, hid,
        cf1, cf2, stats_h, nullptr, nullptr, nullptr, nullptr, nullptr, nullptr);
    k_sgemm<4><<<dim3(8, 16), 128, 0, stream>>>(hid, W2, DIM, slots,
        nullptr, nullptr, nullptr, b2, nullptr, mid,
        last ? o_slots_a : nullptr, last ? o_slots_i : nullptr, nullptr);
    if (!last) k_stats512<<<128, 256, 0, stream>>>(slots, stats_s);
  }

  // ---- final attn + cross outputs (merged renorm) ----
  k_renorm2<<<dim3(512, 2), 256, 0, stream>>>(abuf_a, abuf_i, abufc_a, abufc_i,
      denp, denpc, o_attn_a, o_attn_i, o_cross_ia, o_cross_ai, NA, NI);
}

// Round 15
// 1101.378 us; speedup vs baseline: 1.5806x; 1.5806x over previous
//
#include <hip/hip_runtime.h>
#include <hip/hip_bf16.h>

#define DIM 512
#define EPS 1e-8f
#define LN_EPS 1e-5f
#define SCALE 0.04419417382415922f  // 512^-0.5

typedef float f32x4 __attribute__((ext_vector_type(4)));
typedef __bf16 bf16;
typedef __bf16 bf16x8 __attribute__((ext_vector_type(8)));

typedef const __attribute__((address_space(1))) void gvoid;
typedef __attribute__((address_space(3))) void lvoid;

__device__ inline float bf2f_lo(unsigned u) { union { unsigned x; float f; } c; c.x = u << 16; return c.f; }
__device__ inline float bf2f_hi(unsigned u) { union { unsigned x; float f; } c; c.x = u & 0xffff0000u; return c.f; }

// raw barrier with scheduling fences (rule #18: pin mem ops around s_barrier)
#define SBAR() do { __builtin_amdgcn_sched_barrier(0); \
                    __builtin_amdgcn_s_barrier(); \
                    __builtin_amdgcn_sched_barrier(0); } while (0)

// ---------------------------------------------------------------------------
// Row stats (mean, rstd) + fp32 -> bf16 convert, audio+image merged.
__global__ __launch_bounds__(256) void k_stats_convert(
    const float* __restrict__ xa, const float* __restrict__ xi,
    bf16* __restrict__ xbfa, bf16* __restrict__ xbfi,
    float* __restrict__ sa, float* __restrict__ si, int MA)
{
  int row = blockIdx.x * 4 + (threadIdx.x >> 6);
  int lane = threadIdx.x & 63;
  bool isA = row < MA;
  int lrow = isA ? row : row - MA;
  const float* xr = (isA ? xa : xi) + (size_t)lrow * DIM;
  bf16* xbf = (isA ? xbfa : xbfi) + (size_t)lrow * DIM;
  float* stats = (isA ? sa : si) + (size_t)lrow * 2;
  float4 a = *(const float4*)(xr + lane * 8);
  float4 b = *(const float4*)(xr + lane * 8 + 4);
  float s  = a.x + a.y + a.z + a.w + b.x + b.y + b.z + b.w;
  float ss = a.x*a.x + a.y*a.y + a.z*a.z + a.w*a.w
           + b.x*b.x + b.y*b.y + b.z*b.z + b.w*b.w;
  for (int off = 32; off; off >>= 1) { s += __shfl_xor(s, off); ss += __shfl_xor(ss, off); }
  float mean = s * (1.0f / DIM);
  float var  = ss * (1.0f / DIM) - mean * mean;
  float rs   = rsqrtf(var + LN_EPS);
  if (lane == 0) { stats[0] = mean; stats[1] = rs; }
  union { bf16 h[8]; uint4 u; } cv;
  cv.h[0] = (bf16)a.x; cv.h[1] = (bf16)a.y; cv.h[2] = (bf16)a.z; cv.h[3] = (bf16)a.w;
  cv.h[4] = (bf16)b.x; cv.h[5] = (bf16)b.y; cv.h[6] = (bf16)b.z; cv.h[7] = (bf16)b.w;
  *(uint4*)(xbf + lane * 8) = cv.u;
}

// ---------------------------------------------------------------------------
// Row stats only (512 slot rows), one wave per row.
__global__ __launch_bounds__(256) void k_stats512(
    const float* __restrict__ x, float* __restrict__ stats)
{
  int row = blockIdx.x * 4 + (threadIdx.x >> 6);
  int lane = threadIdx.x & 63;
  const float* xr = x + (size_t)row * DIM;
  float4 a = *(const float4*)(xr + lane * 8);
  float4 b = *(const float4*)(xr + lane * 8 + 4);
  float s  = a.x + a.y + a.z + a.w + b.x + b.y + b.z + b.w;
  float ss = a.x*a.x + a.y*a.y + a.z*a.z + a.w*a.w
           + b.x*b.x + b.y*b.y + b.z*b.z + b.w*b.w;
  for (int off = 32; off; off >>= 1) { s += __shfl_xor(s, off); ss += __shfl_xor(ss, off); }
  float mean = s * (1.0f / DIM);
  float rs   = rsqrtf(ss * (1.0f / DIM) - mean * mean + LN_EPS);
  if (lane == 0) { stats[row * 2] = mean; stats[row * 2 + 1] = rs; }
}

// ---------------------------------------------------------------------------
// Weight prep. rows 0..1023: kv bf16 (g_in fold); 1024..1535: Wq' fp32 (g_s);
// 1536..2047: W1' fp32 (g_f). c1 = sum g*W, c2 = sum b*W + bias (split arrays).
__global__ __launch_bounds__(64) void k_prep(
    const float* __restrict__ Wk, const float* __restrict__ bk,
    const float* __restrict__ Wv, const float* __restrict__ bv,
    const float* __restrict__ g_in, const float* __restrict__ b_in,
    const float* __restrict__ Wq, const float* __restrict__ bq,
    const float* __restrict__ g_s, const float* __restrict__ b_s,
    const float* __restrict__ W1, const float* __restrict__ b1,
    const float* __restrict__ g_f, const float* __restrict__ b_f,
    bf16* __restrict__ wbf, float* __restrict__ c1kv, float* __restrict__ c2kv,
    float* __restrict__ Wqp, float* __restrict__ cq1, float* __restrict__ cq2,
    float* __restrict__ W1p, float* __restrict__ cf1, float* __restrict__ cf2)
{
  int n = blockIdx.x; int lane = threadIdx.x;
  if (n < 1024) {
    const float* W = (n < DIM) ? (Wk + (size_t)n * DIM) : (Wv + (size_t)(n - DIM) * DIM);
    float bias = (n < DIM) ? bk[n] : bv[n - DIM];
    float s1 = 0.f, s2 = 0.f;
    union { bf16 h[8]; uint4 u; } cv;
#pragma unroll
    for (int j = 0; j < 8; ++j) {
      int d = lane * 8 + j;
      float w = W[d];
      float gw = g_in[d] * w;
      s1 += gw; s2 += b_in[d] * w;
      cv.h[j] = (bf16)gw;
    }
    *(uint4*)(wbf + (size_t)n * DIM + lane * 8) = cv.u;
    for (int off = 32; off; off >>= 1) { s1 += __shfl_xor(s1, off); s2 += __shfl_xor(s2, off); }
    if (lane == 0) { c1kv[n] = s1; c2kv[n] = s2 + bias; }
  } else {
    int m; const float* W; float bias; const float* g; const float* b;
    float* Wp; float* cc1; float* cc2;
    if (n < 1536) { m = n - 1024; W = Wq + (size_t)m * DIM; bias = bq[m]; g = g_s; b = b_s; Wp = Wqp; cc1 = cq1; cc2 = cq2; }
    else          { m = n - 1536; W = W1 + (size_t)m * DIM; bias = b1[m]; g = g_f; b = b_f; Wp = W1p; cc1 = cf1; cc2 = cf2; }
    float s1 = 0.f, s2 = 0.f;
    float arr[8];
#pragma unroll
    for (int j = 0; j < 8; ++j) {
      int d = lane * 8 + j;
      float w = W[d];
      float gw = g[d] * w;
      s1 += gw; s2 += b[d] * w;
      arr[j] = gw;
    }
    *(float4*)(Wp + (size_t)m * DIM + lane * 8)     = make_float4(arr[0], arr[1], arr[2], arr[3]);
    *(float4*)(Wp + (size_t)m * DIM + lane * 8 + 4) = make_float4(arr[4], arr[5], arr[6], arr[7]);
    for (int off = 32; off; off >>= 1) { s1 += __shfl_xor(s1, off); s2 += __shfl_xor(s2, off); }
    if (lane == 0) { cc1[m] = s1; cc2[m] = s2 + bias; }
  }
}

// ---------------------------------------------------------------------------
// Merged projection GEMM (audio + image, one dispatch). 128x128 tile, BK=32,
// counted-vmcnt 2-buffer pipeline, setprio, XCD chunking, swapped-operand epi.
__global__ __launch_bounds__(256, 4) void k_kv_gemm(
    const bf16* __restrict__ xa, const bf16* __restrict__ xi,
    const bf16* __restrict__ wbf,
    const float* __restrict__ sa, const float* __restrict__ si,
    const float* __restrict__ c1, const float* __restrict__ c2,
    float* __restrict__ ka, float* __restrict__ ki,
    bf16* __restrict__ kba, bf16* __restrict__ kbi,
    bf16* __restrict__ va, bf16* __restrict__ vi,
    int nblkA, int nblkTot)
{
  __shared__ bf16 As[2][128 * 32];
  __shared__ bf16 Bs[2][128 * 32];
  const int t = threadIdx.x, wave = t >> 6, lane = t & 63;
  int bid = blockIdx.x;
  int rid = (bid & 7) * (nblkTot >> 3) + (bid >> 3);   // XCD chunking
  bool isA = rid < nblkA;
  int lrid = isA ? rid : rid - nblkA;
  const bf16* x = isA ? xa : xi;
  const float* stats = isA ? sa : si;
  float* kout = isA ? ka : ki;
  bf16* kbf = isA ? kba : kbi;
  bf16* vbf = isA ? va : vi;
  const int row0 = (lrid >> 3) * 128, col0 = (lrid & 7) * 128;
  f32x4 acc[4][4] = {};   // acc[ni][mi]: reg axis = N, l15 axis = M

  const int sr  = wave * 16 + (lane >> 2);
  const int sgl = ((lane & 3) ^ ((lane >> 3) & 3)) * 8;
  const bf16* asrc = x   + (size_t)(row0 + sr) * DIM + sgl;
  const bf16* bsrc = wbf + (size_t)(col0 + sr) * DIM + sgl;

  auto stage = [&](int buf, int k0) {    // 4 vmem ops per wave
#pragma unroll
    for (int p = 0; p < 2; ++p) {
      __builtin_amdgcn_global_load_lds(
          (gvoid*)(asrc + (size_t)(p * 64) * DIM + k0),
          (lvoid*)((char*)&As[buf][0] + (p * 256 + wave * 64) * 16), 16, 0, 0);
      __builtin_amdgcn_global_load_lds(
          (gvoid*)(bsrc + (size_t)(p * 64) * DIM + k0),
          (lvoid*)((char*)&Bs[buf][0] + (p * 256 + wave * 64) * 16), 16, 0, 0);
    }
  };

  const int l15 = lane & 15, q16 = lane >> 4;
  const int wm = wave >> 1, wn = wave & 1;
  const int gpx = (q16 ^ ((l15 >> 1) & 3)) * 8;   // physical granule elem offset

  stage(0, 0);
  stage(1, 32);
  asm volatile("s_waitcnt vmcnt(4)" ::: "memory");   // buf0's 4 done
  SBAR();
  int cur = 0;
  for (int ks = 0; ks < 16; ++ks) {
    const bf16* Ab = &As[cur][0];
    const bf16* Bb = &Bs[cur][0];
    bf16x8 ax[4], bw[4];
#pragma unroll
    for (int mi = 0; mi < 4; ++mi)
      ax[mi] = *(const bf16x8*)(Ab + (wm * 64 + mi * 16 + l15) * 32 + gpx);
#pragma unroll
    for (int ni = 0; ni < 4; ++ni)
      bw[ni] = *(const bf16x8*)(Bb + (wn * 64 + ni * 16 + l15) * 32 + gpx);
    __builtin_amdgcn_s_setprio(1);
#pragma unroll
    for (int ni = 0; ni < 4; ++ni)
#pragma unroll
      for (int mi = 0; mi < 4; ++mi)
        acc[ni][mi] = __builtin_amdgcn_mfma_f32_16x16x32_bf16(bw[ni], ax[mi], acc[ni][mi], 0, 0, 0);
    __builtin_amdgcn_s_setprio(0);
    if (ks == 15) break;
    SBAR();                                  // all waves done reading buf cur
    if (ks < 14) {
      stage(cur, (ks + 2) * 32);             // restage freed buf; 8 in flight
      asm volatile("s_waitcnt vmcnt(4)" ::: "memory");  // older 4 done
    } else {
      asm volatile("s_waitcnt vmcnt(0)" ::: "memory");  // last tile done
    }
    SBAR();
    cur ^= 1;
  }

  // epilogue: D[n'][m']: n' = q16*4 + reg (first operand = w), m' = l15 (x)
#pragma unroll
  for (int mi = 0; mi < 4; ++mi) {
    int row = row0 + wm * 64 + mi * 16 + l15;
    float2 st = *(const float2*)&stats[row * 2];   // mean, rstd
    float rs = st.y, rm = st.y * st.x;
#pragma unroll
    for (int ni = 0; ni < 4; ++ni) {
      int col = col0 + wn * 64 + ni * 16 + q16 * 4;
      float4 c1v = *(const float4*)&c1[col];
      float4 c2v = *(const float4*)&c2[col];
      f32x4 a = acc[ni][mi];
      float4 o;
      o.x = rs * a[0] - rm * c1v.x + c2v.x;
      o.y = rs * a[1] - rm * c1v.y + c2v.y;
      o.z = rs * a[2] - rm * c1v.z + c2v.z;
      o.w = rs * a[3] - rm * c1v.w + c2v.w;
      union { bf16 h[4]; uint2 u; } pk;
      pk.h[0] = (bf16)o.x; pk.h[1] = (bf16)o.y; pk.h[2] = (bf16)o.z; pk.h[3] = (bf16)o.w;
      if (col0 < DIM) {
        *(float4*)&kout[(size_t)row * DIM + col] = o;
        if (kbf) *(uint2*)&kbf[(size_t)row * DIM + col] = pk.u;
      } else {
        *(uint2*)&vbf[(size_t)row * DIM + (col - DIM)] = pk.u;
      }
    }
  }
}

// ---------------------------------------------------------------------------
// fp32 -> bf16 convert (fallback when kbf couldn't be fused into the GEMM).
__global__ __launch_bounds__(256) void k_f2bf(
    const float* __restrict__ in, bf16* __restrict__ out)
{
  size_t i = ((size_t)blockIdx.x * 256 + threadIdx.x) * 8;
  float4 a = *(const float4*)(in + i);
  float4 b = *(const float4*)(in + i + 4);
  union { bf16 h[8]; uint4 u; } cv;
  cv.h[0] = (bf16)a.x; cv.h[1] = (bf16)a.y; cv.h[2] = (bf16)a.z; cv.h[3] = (bf16)a.w;
  cv.h[4] = (bf16)b.x; cv.h[5] = (bf16)b.y; cv.h[6] = (bf16)b.z; cv.h[7] = (bf16)b.w;
  *(uint4*)(out + i) = cv.u;
}

// ---------------------------------------------------------------------------
// slots init (both modalities share slots0) + fused row stats. 1 block / row.
__global__ __launch_bounds__(256) void k_init_slots(
    const float* __restrict__ noise, const float* __restrict__ mu,
    const float* __restrict__ lsig, float* __restrict__ slots,
    float* __restrict__ stats)
{
  int row = blockIdx.x;            // 256 rows
  int t = threadIdx.x;
  int d1 = t + 256;
  float v0 = mu[t]  + expf(lsig[t])  * noise[row * DIM + t];
  float v1 = mu[d1] + expf(lsig[d1]) * noise[row * DIM + d1];
  slots[(size_t)row * DIM + t]  = v0;
  slots[(size_t)row * DIM + d1] = v1;
  slots[131072 + (size_t)row * DIM + t]  = v0;
  slots[131072 + (size_t)row * DIM + d1] = v1;
  float s = v0 + v1, ss = v0 * v0 + v1 * v1;
  for (int off = 32; off; off >>= 1) { s += __shfl_xor(s, off); ss += __shfl_xor(ss, off); }
  __shared__ float red[8];
  int wv = t >> 6, ln = t & 63;
  if (ln == 0) { red[wv] = s; red[4 + wv] = ss; }
  __syncthreads();
  if (t == 0) {
    s = red[0] + red[1] + red[2] + red[3];
    ss = red[4] + red[5] + red[6] + red[7];
    float mean = s * (1.0f / DIM);
    float rs = rsqrtf(ss * (1.0f / DIM) - mean * mean + LN_EPS);
    stats[row * 2] = mean; stats[row * 2 + 1] = rs;
    stats[(row + 256) * 2] = mean; stats[(row + 256) * 2 + 1] = rs;
  }
}

// ---------------------------------------------------------------------------
// Small fp32 GEMM over 512 joint rows, K=512. MODE:
// 0 Q:    LN-fold -> qbf (scaled); o_q slices only when outA != nullptr
// 3 MLP1: LN-fold + relu -> C
// 4 MLP2: acc + bias + R -> C (+ optional outA/outI slices)
template <int MODE>
__global__ __launch_bounds__(128) void k_sgemm(
    const float* __restrict__ A, const float* __restrict__ B, int N,
    float* __restrict__ C,
    const float* __restrict__ c1a, const float* __restrict__ c2a,
    const float* __restrict__ stats,
    const float* __restrict__ bias, const float* __restrict__ invden,
    const float* __restrict__ R,
    float* __restrict__ outA, float* __restrict__ outI,
    bf16* __restrict__ qbf)
{
  __shared__ float As[32][33];
  __shared__ float Bs[64][33];
  int t = threadIdx.x;
  int m0 = blockIdx.y * 32, n0 = blockIdx.x * 64;
  float acc[4][4] = {};
  for (int k0 = 0; k0 < DIM; k0 += 32) {
    __syncthreads();
#pragma unroll
    for (int p = 0; p < 2; ++p) {
      int idx = p * 128 + t, r = idx >> 3, c4 = (idx & 7) * 4;
      float4 v = *(const float4*)(A + (size_t)(m0 + r) * DIM + k0 + c4);
      As[r][c4] = v.x; As[r][c4 + 1] = v.y; As[r][c4 + 2] = v.z; As[r][c4 + 3] = v.w;
    }
#pragma unroll
    for (int p = 0; p < 4; ++p) {
      int idx = p * 128 + t, r = idx >> 3, c4 = (idx & 7) * 4;
      float4 v = *(const float4*)(B + (size_t)(n0 + r) * DIM + k0 + c4);
      Bs[r][c4] = v.x; Bs[r][c4 + 1] = v.y; Bs[r][c4 + 2] = v.z; Bs[r][c4 + 3] = v.w;
    }
    __syncthreads();
    int tr = t >> 4, tc = t & 15;
#pragma unroll
    for (int k = 0; k < 32; ++k) {
      float a0 = As[tr * 4][k], a1 = As[tr * 4 + 1][k], a2 = As[tr * 4 + 2][k], a3 = As[tr * 4 + 3][k];
      float b0 = Bs[tc * 4][k], b1 = Bs[tc * 4 + 1][k], b2 = Bs[tc * 4 + 2][k], b3 = Bs[tc * 4 + 3][k];
      acc[0][0] += a0 * b0; acc[0][1] += a0 * b1; acc[0][2] += a0 * b2; acc[0][3] += a0 * b3;
      acc[1][0] += a1 * b0; acc[1][1] += a1 * b1; acc[1][2] += a1 * b2; acc[1][3] += a1 * b3;
      acc[2][0] += a2 * b0; acc[2][1] += a2 * b1; acc[2][2] += a2 * b2; acc[2][3] += a2 * b3;
      acc[3][0] += a3 * b0; acc[3][1] += a3 * b1; acc[3][2] += a3 * b2; acc[3][3] += a3 * b3;
    }
  }
  int tr = t >> 4, tc = t & 15;
#pragma unroll
  for (int mi = 0; mi < 4; ++mi) {
    int row = m0 + tr * 4 + mi;
#pragma unroll
    for (int ni = 0; ni < 4; ++ni) {
      int col = n0 + tc * 4 + ni;
      float v = acc[mi][ni];
      if (MODE == 0 || MODE == 3) {
        float mean = stats[row * 2], rs = stats[row * 2 + 1];
        v = rs * v - rs * mean * c1a[col] + c2a[col];
      }
      if (MODE == 4) v += bias[col];
      if (MODE == 3) v = fmaxf(v, 0.0f);
      if (MODE == 4) v += R[(size_t)row * N + col];
      if (MODE == 0) {
        if (outA) {
          if (row < 256) outA[(size_t)row * DIM + col] = v;
          else           outI[(size_t)(row - 256) * DIM + col] = v;
        }
        qbf[(size_t)row * DIM + col] = (bf16)(v * SCALE);
      } else {
        C[(size_t)row * N + col] = v;
        if (MODE == 4 && outA) {
          if (row < 256) outA[(size_t)row * DIM + col] = v;
          else           outI[(size_t)(row - 256) * DIM + col] = v;
        }
      }
    }
  }
}

// ---------------------------------------------------------------------------
// Fused GRU gate GEMMs: blocks x<24 compute gib = (num @ W_ih^T)*invden + b_ih,
// blocks x>=24 compute ghb = slots @ W_hh^T + b_hh. N = 1536. grid (48, 16).
__global__ __launch_bounds__(128) void k_gates(
    const float* __restrict__ num, const float* __restrict__ slots,
    const float* __restrict__ Wih, const float* __restrict__ Whh,
    const float* __restrict__ bih, const float* __restrict__ bhh,
    const float* __restrict__ invden,
    float* __restrict__ gib, float* __restrict__ ghb)
{
  bool first = blockIdx.x < 24;
  const float* A = first ? num : slots;
  const float* B = first ? Wih : Whh;
  const float* bias = first ? bih : bhh;
  float* C = first ? gib : ghb;
  int n0 = (first ? blockIdx.x : blockIdx.x - 24) * 64;
  int m0 = blockIdx.y * 32;
  __shared__ float As[32][33];
  __shared__ float Bs[64][33];
  int t = threadIdx.x;
  float acc[4][4] = {};
  for (int k0 = 0; k0 < DIM; k0 += 32) {
    __syncthreads();
#pragma unroll
    for (int p = 0; p < 2; ++p) {
      int idx = p * 128 + t, r = idx >> 3, c4 = (idx & 7) * 4;
      float4 v = *(const float4*)(A + (size_t)(m0 + r) * DIM + k0 + c4);
      As[r][c4] = v.x; As[r][c4 + 1] = v.y; As[r][c4 + 2] = v.z; As[r][c4 + 3] = v.w;
    }
#pragma unroll
    for (int p = 0; p < 4; ++p) {
      int idx = p * 128 + t, r = idx >> 3, c4 = (idx & 7) * 4;
      float4 v = *(const float4*)(B + (size_t)(n0 + r) * DIM + k0 + c4);
      Bs[r][c4] = v.x; Bs[r][c4 + 1] = v.y; Bs[r][c4 + 2] = v.z; Bs[r][c4 + 3] = v.w;
    }
    __syncthreads();
    int tr = t >> 4, tc = t & 15;
#pragma unroll
    for (int k = 0; k < 32; ++k) {
      float a0 = As[tr * 4][k], a1 = As[tr * 4 + 1][k], a2 = As[tr * 4 + 2][k], a3 = As[tr * 4 + 3][k];
      float b0 = Bs[tc * 4][k], b1 = Bs[tc * 4 + 1][k], b2 = Bs[tc * 4 + 2][k], b3 = Bs[tc * 4 + 3][k];
      acc[0][0] += a0 * b0; acc[0][1] += a0 * b1; acc[0][2] += a0 * b2; acc[0][3] += a0 * b3;
      acc[1][0] += a1 * b0; acc[1][1] += a1 * b1; acc[1][2] += a1 * b2; acc[1][3] += a1 * b3;
      acc[2][0] += a2 * b0; acc[2][1] += a2 * b1; acc[2][2] += a2 * b2; acc[2][3] += a2 * b3;
      acc[3][0] += a3 * b0; acc[3][1] += a3 * b1; acc[3][2] += a3 * b2; acc[3][3] += a3 * b3;
    }
  }
  int tr = t >> 4, tc = t & 15;
#pragma unroll
  for (int mi = 0; mi < 4; ++mi) {
    int row = m0 + tr * 4 + mi;
    float sc = first ? invden[row] : 1.0f;
#pragma unroll
    for (int ni = 0; ni < 4; ++ni) {
      int col = n0 + tc * 4 + ni;
      C[(size_t)row * 1536 + col] = acc[mi][ni] * sc + bias[col];
    }
  }
}

// ---------------------------------------------------------------------------
// FUSED dots + slot-softmax + a@v partials. Phase 2: 16B/lane v loads
// (dim-group x row-group decomposition) + LDS reduce across row-groups.
template <int LAST>
__global__ __launch_bounds__(256) void k_dots_upd(
    const bf16* __restrict__ qA, const bf16* __restrict__ qI,
    const bf16* __restrict__ kA, const bf16* __restrict__ kI,
    const bf16* __restrict__ vA, const bf16* __restrict__ vI,
    float* __restrict__ aoutA, float* __restrict__ aoutI,
    float* __restrict__ acA, float* __restrict__ acI,
    float* __restrict__ denp, float* __restrict__ denpc,
    float* __restrict__ numpA, float* __restrict__ numpI,
    int NA_, int NI_)
{
  __shared__ bf16 ks[2][128 * 64];   // 32 KB, swizzled k tiles / phase-2 scratch
  __shared__ float ash[128 * 12];    // 6 KB a-tile
  __shared__ float dsh[64];
  int t = threadIdx.x, wave = t >> 6, lane = t & 63;
  int b = blockIdx.y, tile = blockIdx.x;
  bool isA = tile < 8;
  int til = isA ? tile : tile - 8;
  int N = isA ? NA_ : NI_;
  int nc = isA ? 8 : 25;
  int j0 = til * 128;
  const bf16* qo = (isA ? qA : qI) + (size_t)b * 8 * DIM;
  const bf16* qc = (isA ? qI : qA) + (size_t)b * 8 * DIM;
  const bf16* k  = (isA ? kA : kI) + (size_t)b * N * DIM;
  const bf16* v  = (isA ? vA : vI) + (size_t)b * N * DIM;
  float* aout = (isA ? aoutA : aoutI) + (LAST ? (size_t)b * 8 * N : 0);
  float* aco  = (isA ? acA  : acI ) + (LAST ? (size_t)b * 8 * N : 0);
  int drow = (isA ? 0 : 256) + b * 8;

  const int l15 = lane & 15, q16 = lane >> 4;
  bf16x8 afq[16], afqc[16];
  {
    const bf16* qr = qo + (size_t)(l15 & 7) * DIM + q16 * 8;
#pragma unroll
    for (int f = 0; f < 16; ++f) afq[f] = *(const bf16x8*)(qr + f * 32);
  }
  if (LAST) {
    const bf16* qr = qc + (size_t)(l15 & 7) * DIM + q16 * 8;
#pragma unroll
    for (int f = 0; f < 16; ++f) afqc[f] = *(const bf16x8*)(qr + f * 32);
  }

  const int sr  = wave * 8 + (lane >> 3);
  const int sgl = ((lane & 7) ^ (lane >> 3)) * 8;
  int jr = j0 + sr; if (jr > N - 1) jr = N - 1;
  const bf16* ksrc = k + (size_t)jr * DIM + sgl;
  int jr2 = j0 + 32 + sr; if (jr2 > N - 1) jr2 = N - 1;
  const bf16* ksrc2 = k + (size_t)jr2 * DIM + sgl;
  int jr3 = j0 + 64 + sr; if (jr3 > N - 1) jr3 = N - 1;
  const bf16* ksrc3 = k + (size_t)jr3 * DIM + sgl;
  int jr4 = j0 + 96 + sr; if (jr4 > N - 1) jr4 = N - 1;
  const bf16* ksrc4 = k + (size_t)jr4 * DIM + sgl;

  auto stage = [&](int buf, int c) {   // 4 vmem ops per wave
    __builtin_amdgcn_global_load_lds((gvoid*)(ksrc  + c * 64),
        (lvoid*)((char*)&ks[0][0] + buf * 16384 + (0 * 256 + wave * 64) * 16), 16, 0, 0);
    __builtin_amdgcn_global_load_lds((gvoid*)(ksrc2 + c * 64),
        (lvoid*)((char*)&ks[0][0] + buf * 16384 + (1 * 256 + wave * 64) * 16), 16, 0, 0);
    __builtin_amdgcn_global_load_lds((gvoid*)(ksrc3 + c * 64),
        (lvoid*)((char*)&ks[0][0] + buf * 16384 + (2 * 256 + wave * 64) * 16), 16, 0, 0);
    __builtin_amdgcn_global_load_lds((gvoid*)(ksrc4 + c * 64),
        (lvoid*)((char*)&ks[0][0] + buf * 16384 + (3 * 256 + wave * 64) * 16), 16, 0, 0);
  };

  stage(0, 0);
  stage(1, 1);
  asm volatile("s_waitcnt vmcnt(4)" ::: "memory");
  SBAR();
  f32x4 acc[2] = {}, accc[2] = {};
  int cur = 0;
  for (int c = 0; c < 8; ++c) {
    const bf16* kb = &ks[0][0] + cur * (128 * 64);
    __builtin_amdgcn_s_setprio(1);
#pragma unroll
    for (int kk = 0; kk < 2; ++kk) {
#pragma unroll
      for (int n = 0; n < 2; ++n) {
        int R = wave * 32 + n * 16 + l15;
        int gp = (kk * 4 + q16) ^ (R & 7);
        bf16x8 bfr = *(const bf16x8*)(kb + R * 64 + gp * 8);
        acc[n] = __builtin_amdgcn_mfma_f32_16x16x32_bf16(afq[c * 2 + kk], bfr, acc[n], 0, 0, 0);
        if (LAST)
          accc[n] = __builtin_amdgcn_mfma_f32_16x16x32_bf16(afqc[c * 2 + kk], bfr, accc[n], 0, 0, 0);
      }
    }
    __builtin_amdgcn_s_setprio(0);
    if (c == 7) break;
    SBAR();
    if (c < 6) {
      stage(cur, c + 2);
      asm volatile("s_waitcnt vmcnt(4)" ::: "memory");
    } else {
      asm volatile("s_waitcnt vmcnt(0)" ::: "memory");
    }
    SBAR();
    cur ^= 1;
  }

  // epilogue: q16 groups hold slots 0-3 / 4-7 for token col = lane&15
  float dsum[8], dsumc[8];
#pragma unroll
  for (int i = 0; i < 8; ++i) { dsum[i] = 0.f; dsumc[i] = 0.f; }
#pragma unroll
  for (int n = 0; n < 2; ++n) {
    int jloc = wave * 32 + n * 16 + l15;
    int j = j0 + jloc;
    bool valid = (j < N);
    {
      float dv[8];
#pragma unroll
      for (int r = 0; r < 4; ++r) {
        float own = acc[n][r];
        float oth = __shfl_xor(own, 16);
        if (q16 == 0) { dv[r] = own; dv[4 + r] = oth; }
        else          { dv[r] = oth; dv[4 + r] = own; }
      }
      float mx = dv[0];
#pragma unroll
      for (int i = 1; i < 8; ++i) mx = fmaxf(mx, dv[i]);
      float sum = 0.f;
#pragma unroll
      for (int i = 0; i < 8; ++i) { dv[i] = __expf(dv[i] - mx); sum += dv[i]; }
      float inv = 1.0f / sum;
#pragma unroll
      for (int i = 0; i < 8; ++i) {
        float av = valid ? dv[i] * inv : 0.0f;
        dsum[i] += av;
        if (q16 == 0) {
          ash[jloc * 12 + i] = av;
          if (LAST && valid) aout[(size_t)i * N + j] = av;
        }
      }
    }
    if (LAST) {
      float dv[8];
#pragma unroll
      for (int r = 0; r < 4; ++r) {
        float own = accc[n][r];
        float oth = __shfl_xor(own, 16);
        if (q16 == 0) { dv[r] = own; dv[4 + r] = oth; }
        else          { dv[r] = oth; dv[4 + r] = own; }
      }
      float mx = dv[0];
#pragma unroll
      for (int i = 1; i < 8; ++i) mx = fmaxf(mx, dv[i]);
      float sum = 0.f;
#pragma unroll
      for (int i = 0; i < 8; ++i) { dv[i] = __expf(dv[i] - mx); sum += dv[i]; }
      float inv = 1.0f / sum;
#pragma unroll
      for (int i = 0; i < 8; ++i) {
        float av = valid ? dv[i] * inv : 0.0f;
        dsumc[i] += av;
        if (q16 == 0 && valid) aco[(size_t)i * N + j] = av;
      }
    }
  }
#pragma unroll
  for (int i = 0; i < 8; ++i) {
    float x1 = dsum[i];
    x1 += __shfl_xor(x1, 1); x1 += __shfl_xor(x1, 2);
    x1 += __shfl_xor(x1, 4); x1 += __shfl_xor(x1, 8);
    dsum[i] = x1;
    if (LAST) {
      float x2 = dsumc[i];
      x2 += __shfl_xor(x2, 1); x2 += __shfl_xor(x2, 2);
      x2 += __shfl_xor(x2, 4); x2 += __shfl_xor(x2, 8);
      dsumc[i] = x2;
    }
  }
  if (lane == 0) {
#pragma unroll
    for (int i = 0; i < 8; ++i) {
      dsh[wave * 8 + i] = dsum[i];
      if (LAST) dsh[32 + wave * 8 + i] = dsumc[i];
    }
  }
  __syncthreads();   // also: all ks reads (MFMA phase) complete past here
  if (t < 8) {
    denp[((size_t)drow + t) * 32 + til] = dsh[t] + dsh[8 + t] + dsh[16 + t] + dsh[24 + t];
  }
  if (LAST && t >= 8 && t < 16) {
    int i = t - 8;
    denpc[((size_t)drow + i) * 32 + til] = dsh[32 + i] + dsh[40 + i] + dsh[48 + i] + dsh[56 + i];
  }

  // ---- phase 2: num partial = a(tile) @ v(tile), 16B/lane v loads ----
  int dg = t & 63, rg = t >> 6;
  float ua[8][8];
#pragma unroll
  for (int i = 0; i < 8; ++i)
#pragma unroll
    for (int j = 0; j < 8; ++j) ua[i][j] = 0.f;
  for (int jj = rg; jj < 128; jj += 4) {
    int jv = j0 + jj; if (jv > N - 1) jv = N - 1;   // a==0 for padded rows
    uint4 vv = *(const uint4*)(v + (size_t)jv * DIM + dg * 8);
    float vf[8];
    vf[0] = bf2f_lo(vv.x); vf[1] = bf2f_hi(vv.x);
    vf[2] = bf2f_lo(vv.y); vf[3] = bf2f_hi(vv.y);
    vf[4] = bf2f_lo(vv.z); vf[5] = bf2f_hi(vv.z);
    vf[6] = bf2f_lo(vv.w); vf[7] = bf2f_hi(vv.w);
    float4 a0 = *(const float4*)&ash[jj * 12];
    float4 a1 = *(const float4*)&ash[jj * 12 + 4];
    float aw[8] = {a0.x, a0.y, a0.z, a0.w, a1.x, a1.y, a1.z, a1.w};
#pragma unroll
    for (int i = 0; i < 8; ++i)
#pragma unroll
      for (int j = 0; j < 8; ++j)
        ua[i][j] += aw[i] * vf[j];
  }
  float* red2 = (float*)&ks[0][0];   // 32 KB scratch: [16][512] f32
  float* np = (isA ? numpA : numpI) + (((size_t)b * nc + til) * 8) * DIM;
#pragma unroll
  for (int sg = 0; sg < 2; ++sg) {
    __syncthreads();
#pragma unroll
    for (int i4 = 0; i4 < 4; ++i4) {
      int i = sg * 4 + i4;
      *(float4*)&red2[(i4 * 4 + rg) * 512 + dg * 8]     = make_float4(ua[i][0], ua[i][1], ua[i][2], ua[i][3]);
      *(float4*)&red2[(i4 * 4 + rg) * 512 + dg * 8 + 4] = make_float4(ua[i][4], ua[i][5], ua[i][6], ua[i][7]);
    }
    __syncthreads();
    {
      int i4r = t >> 6;          // slot within group
      int d0r = (t & 63) * 8;    // 8 consecutive dims
      float o[8];
#pragma unroll
      for (int j = 0; j < 8; ++j) {
        int d = d0r + j;
        o[j] = red2[(i4r * 4 + 0) * 512 + d] + red2[(i4r * 4 + 1) * 512 + d]
             + red2[(i4r * 4 + 2) * 512 + d] + red2[(i4r * 4 + 3) * 512 + d];
      }
      *(float4*)&np[(size_t)(sg * 4 + i4r) * DIM + d0r]     = make_float4(o[0], o[1], o[2], o[3]);
      *(float4*)&np[(size_t)(sg * 4 + i4r) * DIM + d0r + 4] = make_float4(o[4], o[5], o[6], o[7]);
    }
  }
}

// ---------------------------------------------------------------------------
// num reduce over tile partials + invden = 1/(sum denp + EPS). 1 block / row.
__global__ __launch_bounds__(256) void k_numred(
    const float* __restrict__ numpA, const float* __restrict__ numpI,
    const float* __restrict__ denp,
    float* __restrict__ num, float* __restrict__ invden)
{
  int m = blockIdx.x, t = threadIdx.x;
  bool isA = m < 256;
  int mm = isA ? m : m - 256;
  int bb = mm >> 3, i = mm & 7;
  int nc = isA ? 8 : 25;
  const float* np = (isA ? numpA : numpI) + (((size_t)bb * nc) * 8 + i) * DIM;
  int d0 = t * 2;
  float s0 = 0.f, s1 = 0.f;
  for (int c = 0; c < nc; ++c) {
    float2 vv = *(const float2*)&np[(size_t)c * 8 * DIM + d0];
    s0 += vv.x; s1 += vv.y;
  }
  *(float2*)&num[(size_t)m * DIM + d0] = make_float2(s0, s1);
  if (t == 0) {
    float den = EPS;
    for (int c2 = 0; c2 < nc; ++c2) den += denp[(size_t)m * 32 + c2];
    invden[m] = 1.0f / den;
  }
}

// ---------------------------------------------------------------------------
// GRU pointwise (gate order r,z,n) + stats of h. One block per row.
__global__ __launch_bounds__(256) void k_gru(
    const float* __restrict__ gi, const float* __restrict__ gh,
    const float* __restrict__ prev,
    float* __restrict__ hout, float* __restrict__ stats_h)
{
  int m = blockIdx.x; int t = threadIdx.x;
  size_t b3 = (size_t)m * 1536, b1 = (size_t)m * DIM;
  float h[2]; float s = 0.f, ss = 0.f;
#pragma unroll
  for (int p = 0; p < 2; ++p) {
    int d = t + p * 256;
    float ir = gi[b3 + d], iz = gi[b3 + 512 + d], in_ = gi[b3 + 1024 + d];
    float hr = gh[b3 + d], hz = gh[b3 + 512 + d], hn = gh[b3 + 1024 + d];
    float r = 1.f / (1.f + __expf(-(ir + hr)));
    float z = 1.f / (1.f + __expf(-(iz + hz)));
    float n = tanhf(in_ + r * hn);
    float hv = (1.f - z) * n + z * prev[b1 + d];
    hout[b1 + d] = hv;
    h[p] = hv; s += hv; ss += hv * hv;
  }
  for (int off = 32; off; off >>= 1) { s += __shfl_xor(s, off); ss += __shfl_xor(ss, off); }
  __shared__ float red[8];
  int wv = t >> 6, ln = t & 63;
  if (ln == 0) { red[wv] = s; red[4 + wv] = ss; }
  __syncthreads();
  s = red[0] + red[1] + red[2] + red[3];
  ss = red[4] + red[5] + red[6] + red[7];
  float mean = s * (1.0f / DIM);
  float rs = rsqrtf(ss * (1.0f / DIM) - mean * mean + LN_EPS);
  if (t == 0) { stats_h[m * 2] = mean; stats_h[m * 2 + 1] = rs; }
}

// ---------------------------------------------------------------------------
// attn/cross = a / (sum_j a + EPS). grid (512, 2): y=0 own attn, y=1 cross.
__global__ __launch_bounds__(256) void k_renorm2(
    const float* __restrict__ aA, const float* __restrict__ aI,
    const float* __restrict__ acA, const float* __restrict__ acI,
    const float* __restrict__ denp, const float* __restrict__ denpc,
    float* __restrict__ oaA, float* __restrict__ oaI,
    float* __restrict__ ocIA, float* __restrict__ ocAI, int NA_, int NI_)
{
  int m = blockIdx.x; int t = threadIdx.x;
  bool cr = blockIdx.y != 0;
  bool isA = m < 256;
  int mm = isA ? m : m - 256;
  int N = isA ? NA_ : NI_;
  int nch = isA ? 8 : 25;
  const float* in = (cr ? (isA ? acA : acI) : (isA ? aA : aI)) + (size_t)mm * N;
  const float* dp = cr ? denpc : denp;
  float* out = (cr ? (isA ? ocIA : ocAI) : (isA ? oaA : oaI)) + (size_t)mm * N;
  float den = EPS;
  for (int c = 0; c < nch; ++c) den += dp[(size_t)m * 32 + c];
  float inv = 1.0f / den;
  for (int idx = t; idx * 4 < N; idx += 256) {
    float4 v = *(const float4*)&in[idx * 4];
    v.x *= inv; v.y *= inv; v.z *= inv; v.w *= inv;
    *(float4*)&out[idx * 4] = v;
  }
}

// ---------------------------------------------------------------------------
extern "C" void kernel_launch(void* const* d_in, const int* in_sizes, int n_in,
                              void* d_out, int out_size, void* d_ws, size_t ws_size,
                              hipStream_t stream)
{
  (void)in_sizes; (void)n_in; (void)out_size;
  const float* x_a   = (const float*)d_in[0];
  const float* x_i   = (const float*)d_in[1];
  const float* noise = (const float*)d_in[2];
  const float* mu    = (const float*)d_in[3];
  const float* lsig  = (const float*)d_in[4];
  const float* ln_in_g = (const float*)d_in[5];
  const float* ln_in_b = (const float*)d_in[6];
  const float* ln_s_g  = (const float*)d_in[7];
  const float* ln_s_b  = (const float*)d_in[8];
  const float* ln_f_g  = (const float*)d_in[9];
  const float* ln_f_b  = (const float*)d_in[10];
  const float* Wq = (const float*)d_in[11]; const float* bq = (const float*)d_in[12];
  const float* Wk = (const float*)d_in[13]; const float* bk = (const float*)d_in[14];
  const float* Wv = (const float*)d_in[15]; const float* bv = (const float*)d_in[16];
  const float* W_ih = (const float*)d_in[17]; const float* W_hh = (const float*)d_in[18];
  const float* b_ih = (const float*)d_in[19]; const float* b_hh = (const float*)d_in[20];
  const float* W1 = (const float*)d_in[21]; const float* b1 = (const float*)d_in[22];
  const float* W2 = (const float*)d_in[23]; const float* b2 = (const float*)d_in[24];

  const int NA = 1024, NI = 3136;
  const int MA = 32 * NA, MI = 32 * NI;     // 32768, 100352

  float* out = (float*)d_out;
  float* o_slots_a  = out;
  float* o_q_a      = out + 131072;
  float* o_k_a      = out + 262144;
  float* o_attn_a   = out + 17039360;
  float* o_cross_ia = out + 17301504;
  float* o_slots_i  = out + 17563648;
  float* o_q_i      = out + 17694720;
  float* o_k_i      = out + 17825792;
  float* o_attn_i   = out + 69206016;
  float* o_cross_ai = out + 70008832;

  // ---- workspace carve ----
  char* w = (char*)d_ws;
  size_t used = 0;
  auto alloc = [&](size_t bytes) {
    char* p = w + used;
    used += (bytes + 255) & ~(size_t)255;
    return p;
  };
  bf16* xbf_a = (bf16*)alloc((size_t)MA * DIM * 2);
  bf16* xbf_i = (bf16*)alloc((size_t)MI * DIM * 2);
  bf16* vbf_a = (bf16*)alloc((size_t)MA * DIM * 2);
  bf16* vbf_i = (bf16*)alloc((size_t)MI * DIM * 2);
  float* stats_a = (float*)alloc((size_t)MA * 2 * 4);
  float* stats_i = (float*)alloc((size_t)MI * 2 * 4);
  bf16* wbf  = (bf16*)alloc(1024 * 512 * 2);
  float* c1kv = (float*)alloc(1024 * 4);
  float* c2kv = (float*)alloc(1024 * 4);
  float* Wqp = (float*)alloc(512 * 512 * 4);
  float* cq1 = (float*)alloc(512 * 4);
  float* cq2 = (float*)alloc(512 * 4);
  float* W1p = (float*)alloc(512 * 512 * 4);
  float* cf1 = (float*)alloc(512 * 4);
  float* cf2 = (float*)alloc(512 * 4);
  float* slots = (float*)alloc(512 * 512 * 4);
  bf16*  qbf   = (bf16*)alloc(512 * 512 * 2);
  float* mid   = (float*)alloc(512 * 512 * 4);
  float* hid   = (float*)alloc(512 * 512 * 4);
  float* num   = (float*)alloc(512 * 512 * 4);
  float* gib   = (float*)alloc(512 * 1536 * 4);
  float* ghb   = (float*)alloc(512 * 1536 * 4);
  float* stats_s = (float*)alloc(512 * 2 * 4);
  float* stats_h = (float*)alloc(512 * 2 * 4);
  float* invden  = (float*)alloc(512 * 4);
  float* denp    = (float*)alloc(512 * 32 * 4);
  float* denpc   = (float*)alloc(512 * 32 * 4);
  float* abuf_a  = (float*)alloc((size_t)256 * NA * 4);
  float* abuf_i  = (float*)alloc((size_t)256 * NI * 4);
  float* abufc_a = (float*)alloc((size_t)256 * NA * 4);
  float* abufc_i = (float*)alloc((size_t)256 * NI * 4);
  float* numpA   = (float*)alloc((size_t)32 * 8 * 8 * DIM * 4);
  float* numpI   = (float*)alloc((size_t)32 * 25 * 8 * DIM * 4);
  if (used > ws_size) return;   // base ws too small -> diagnosable poison

  size_t kbf_bytes = (((size_t)MA * DIM * 2 + 255) & ~(size_t)255)
                   + (((size_t)MI * DIM * 2 + 255) & ~(size_t)255);
  bf16* kbf_a; bf16* kbf_i; bool kbf_fused;
  if (used + kbf_bytes <= ws_size) {
    kbf_a = (bf16*)alloc((size_t)MA * DIM * 2);
    kbf_i = (bf16*)alloc((size_t)MI * DIM * 2);
    kbf_fused = true;
  } else {
    kbf_a = xbf_a; kbf_i = xbf_i;   // reuse, filled by k_f2bf after the GEMMs
    kbf_fused = false;
  }

  // ---- phase 1 ----
  k_stats_convert<<<(MA + MI) / 4, 256, 0, stream>>>(x_a, x_i, xbf_a, xbf_i,
                                                     stats_a, stats_i, MA);
  k_prep<<<2048, 64, 0, stream>>>(Wk, bk, Wv, bv, ln_in_g, ln_in_b,
                                  Wq, bq, ln_s_g, ln_s_b, W1, b1, ln_f_g, ln_f_b,
                                  wbf, c1kv, c2kv, Wqp, cq1, cq2, W1p, cf1, cf2);
  {
    int nblkA = (MA / 128) * 8;           // 2048
    int nblkTot = nblkA + (MI / 128) * 8; // 8320 (divisible by 8)
    k_kv_gemm<<<nblkTot, 256, 0, stream>>>(xbf_a, xbf_i, wbf, stats_a, stats_i,
        c1kv, c2kv, o_k_a, o_k_i,
        kbf_fused ? kbf_a : nullptr, kbf_fused ? kbf_i : nullptr,
        vbf_a, vbf_i, nblkA, nblkTot);
  }
  if (!kbf_fused) {
    k_f2bf<<<MA * DIM / 2048, 256, 0, stream>>>(o_k_a, kbf_a);
    k_f2bf<<<MI * DIM / 2048, 256, 0, stream>>>(o_k_i, kbf_i);
  }
  k_init_slots<<<256, 256, 0, stream>>>(noise, mu, lsig, slots, stats_s);

  // ---- iterations ----
  for (int it = 0; it < 3; ++it) {
    bool last = (it == 2);
    // q = LN(slots) @ Wq' + fold  -> qbf (scaled); o_q only on last iter
    k_sgemm<0><<<dim3(8, 16), 128, 0, stream>>>(slots, Wqp, DIM, nullptr,
        cq1, cq2, stats_s, nullptr, nullptr, nullptr,
        last ? o_q_a : nullptr, last ? o_q_i : nullptr, qbf);
    // fused dots + softmax + a@v partials (+ cross dots on last iter)
    if (!last)
      k_dots_upd<0><<<dim3(33, 32), 256, 0, stream>>>(qbf, qbf + 256 * DIM,
          kbf_a, kbf_i, vbf_a, vbf_i,
          nullptr, nullptr, nullptr, nullptr, denp, nullptr,
          numpA, numpI, NA, NI);
    else
      k_dots_upd<1><<<dim3(33, 32), 256, 0, stream>>>(qbf, qbf + 256 * DIM,
          kbf_a, kbf_i, vbf_a, vbf_i,
          abuf_a, abuf_i, abufc_a, abufc_i, denp, denpc,
          numpA, numpI, NA, NI);
    k_numred<<<512, 256, 0, stream>>>(numpA, numpI, denp, num, invden);
    // fused GRU gate GEMMs
    k_gates<<<dim3(48, 16), 128, 0, stream>>>(num, slots, W_ih, W_hh,
        b_ih, b_hh, invden, gib, ghb);
    k_gru<<<512, 256, 0, stream>>>(gib, ghb, slots, mid, stats_h);
    // MLP (ln_ff folded into W1')
    k_sgemm<3><<<dim3(8, 16), 128, 0, stream>>>(mid, W1p, DIM, hid,
        cf1, cf2, stats_h, nullptr, nullptr, nullptr, nullptr, nullptr, nullptr);
    k_sgemm<4><<<dim3(8, 16), 128, 0, stream>>>(hid, W2, DIM, slots,
        nullptr, nullptr, nullptr, b2, nullptr, mid,
        last ? o_slots_a : nullptr, last ? o_slots_i : nullptr, nullptr);
    if (!last) k_stats512<<<128, 256, 0, stream>>>(slots, stats_s);
  }

  // ---- final attn + cross outputs (merged renorm) ----
  k_renorm2<<<dim3(512, 2), 256, 0, stream>>>(abuf_a, abuf_i, abufc_a, abufc_i,
      denp, denpc, o_attn_a, o_attn_i, o_cross_ia, o_cross_ai, NA, NI);
}